// Round 8
// baseline (1424.070 us; speedup 1.0000x reference)
//
#include <hip/hip_runtime.h>

// Problem constants: B=N=256, D=S=1024
// out = [ctx 256*1024 fp32 ; W 256*256*1024 fp32]

typedef _Float16 half8 __attribute__((ext_vector_type(8)));
typedef _Float16 half4 __attribute__((ext_vector_type(4)));
typedef float floatx16 __attribute__((ext_vector_type(16)));

static __device__ __forceinline__ void split_f32(float x, _Float16& hi, _Float16& lo) {
    _Float16 h = (_Float16)x;
    hi = h;
    lo = (_Float16)(x - (float)h);
}

// ---------------------------------------------------------------------------
// GEMM body: C[M,N] = A[M,K] @ B, fp32 in, hi/lo fp16 split on BOTH operands
// (3 MFMAs). Tile 64x64, 256 threads, BK=32. SPLITK: grid.z K-slices, fp32
// atomicAdd epilogue (R6: filled the machine, saved ~70 us on the small gemms).
// ---------------------------------------------------------------------------
template <bool BT, bool SPLITK>
__device__ __forceinline__ void gemm_body(
    const float* __restrict__ Ag, const float* __restrict__ Bg,
    float* __restrict__ Cf, int Kdim, int Ndim, int KC, int bx, int by, int bz)
{
    __shared__ __align__(16) _Float16 AsHi[4 * 64 * 8];
    __shared__ __align__(16) _Float16 AsLo[4 * 64 * 8];
    __shared__ __align__(16) _Float16 BsHi[4 * 64 * 8];
    __shared__ __align__(16) _Float16 BsLo[4 * 64 * 8];

    const int tid  = threadIdx.x;
    const int lane = tid & 63;
    const int wave = tid >> 6;
    const int wy = wave >> 1, wx = wave & 1;
    const int l31 = lane & 31, l5 = lane >> 5;
    const int m0 = by * 64, n0 = bx * 64;
    const int kt0 = (bz * KC) >> 5;

    floatx16 acc;
#pragma unroll
    for (int j = 0; j < 16; ++j) acc[j] = 0.0f;

    const int sA_m  = tid >> 2;
    const int sA_kg = tid & 3;
    const int sB_n  = tid & 63;
    const int sB_kg = tid >> 6;

    const int nkt = KC / 32;
#pragma unroll 1
    for (int kt2 = 0; kt2 < nkt; ++kt2) {
        const int kt = kt0 + kt2;
        __syncthreads();
        {   // stage A chunk [32k x 64m] -> [kg][m][8] hi/lo
            const float* src = Ag + (size_t)(m0 + sA_m) * Kdim + kt * 32 + sA_kg * 8;
            half8 hi, lo;
#pragma unroll
            for (int j = 0; j < 8; ++j) {
                _Float16 h, l;
                split_f32(src[j], h, l);
                hi[j] = h; lo[j] = l;
            }
            *(half8*)&AsHi[(sA_kg * 64 + sA_m) * 8] = hi;
            *(half8*)&AsLo[(sA_kg * 64 + sA_m) * 8] = lo;
        }
        if constexpr (BT) {
            const float* src = Bg + (size_t)(n0 + sA_m) * Kdim + kt * 32 + sA_kg * 8;
            half8 hi, lo;
#pragma unroll
            for (int j = 0; j < 8; ++j) {
                _Float16 h, l;
                split_f32(src[j], h, l);
                hi[j] = h; lo[j] = l;
            }
            *(half8*)&BsHi[(sA_kg * 64 + sA_m) * 8] = hi;
            *(half8*)&BsLo[(sA_kg * 64 + sA_m) * 8] = lo;
        } else {
            const float* src = Bg + (size_t)(kt * 32 + sB_kg * 8) * Ndim + n0 + sB_n;
            half8 hi, lo;
#pragma unroll
            for (int j = 0; j < 8; ++j) {
                _Float16 h, l;
                split_f32(src[(size_t)j * Ndim], h, l);
                hi[j] = h; lo[j] = l;
            }
            *(half8*)&BsHi[(sB_kg * 64 + sB_n) * 8] = hi;
            *(half8*)&BsLo[(sB_kg * 64 + sB_n) * 8] = lo;
        }
        __syncthreads();
#pragma unroll
        for (int ks = 0; ks < 2; ++ks) {
            const int kg = ks * 2 + l5;
            const half8 ah = *(half8*)&AsHi[(kg * 64 + wy * 32 + l31) * 8];
            const half8 al = *(half8*)&AsLo[(kg * 64 + wy * 32 + l31) * 8];
            const half8 bh = *(half8*)&BsHi[(kg * 64 + wx * 32 + l31) * 8];
            const half8 bl = *(half8*)&BsLo[(kg * 64 + wx * 32 + l31) * 8];
            acc = __builtin_amdgcn_mfma_f32_32x32x16_f16(ah, bh, acc, 0, 0, 0);
            acc = __builtin_amdgcn_mfma_f32_32x32x16_f16(ah, bl, acc, 0, 0, 0);
            acc = __builtin_amdgcn_mfma_f32_32x32x16_f16(al, bh, acc, 0, 0, 0);
        }
    }

    // C/D layout (verified): col = lane&31, row = (reg&3) + 8*(reg>>2) + 4*(lane>>5)
#pragma unroll
    for (int reg = 0; reg < 16; ++reg) {
        const int row = m0 + wy * 32 + (reg & 3) + 8 * (reg >> 2) + 4 * l5;
        const int col = n0 + wx * 32 + l31;
        if constexpr (SPLITK) atomicAdd(&Cf[(size_t)row * Ndim + col], acc[reg]);
        else                  Cf[(size_t)row * Ndim + col] = acc[reg];
    }
}

template <bool BT>
__global__ __launch_bounds__(256, 2) void gemm_splitk(
    const float* __restrict__ Ag, const float* __restrict__ Bg,
    float* __restrict__ Cf, int Kdim, int Ndim, int KC)
{
    gemm_body<BT, true>(Ag, Bg, Cf, Kdim, Ndim, KC,
                        blockIdx.x, blockIdx.y, blockIdx.z);
}

// ---------------------------------------------------------------------------
// Transpose body (R5, proven): FV16T[i][d][n] = fp16(FV[i][n][d]) for one
// (i, 64-d tile). Coalesced float4 reads -> padded LDS -> coalesced b128
// writes of FV16T.
// ---------------------------------------------------------------------------
__device__ __forceinline__ void transpose_body(
    const float* __restrict__ FV, _Float16* __restrict__ T, int i, int dt)
{
    __shared__ __align__(16) _Float16 tb[64 * 264];
    const int tid = threadIdx.x;
    const int dl = tid & 15;
    const int nq = tid >> 4;
    const float* src = FV + (size_t)i * 256 * 1024 + (size_t)dt * 64;

#pragma unroll
    for (int p = 0; p < 4; ++p) {
        const int n0 = p * 64 + nq * 4;
        float4 v[4];
#pragma unroll
        for (int r = 0; r < 4; ++r)
            v[r] = *(const float4*)(src + (size_t)(n0 + r) * 1024 + dl * 4);
#pragma unroll
        for (int q = 0; q < 4; ++q) {
            half4 h;
            h[0] = (_Float16)((&v[0].x)[q]);
            h[1] = (_Float16)((&v[1].x)[q]);
            h[2] = (_Float16)((&v[2].x)[q]);
            h[3] = (_Float16)((&v[3].x)[q]);
            *(half4*)&tb[(size_t)(dl * 4 + q) * 264 + n0] = h;
        }
    }
    __syncthreads();
    const int s = tid & 31, dg = tid >> 5;
#pragma unroll
    for (int q = 0; q < 8; ++q) {
        const int d = dg * 8 + q;
        const half8 h = *(half8*)&tb[(size_t)d * 264 + s * 8];
        *(half8*)(T + ((size_t)i * 1024 + dt * 64 + d) * 256 + s * 8) = h;
    }
}

// Combined: gemm1 (A1 = state @ Q^T, 64 blocks) + FV transpose (4096 blocks)
// in one dispatch (transpose blocks fill the machine; gemm1 tail hides).
__global__ __launch_bounds__(256, 2) void gemm1_plus_transpose(
    const float* __restrict__ state, const float* __restrict__ Q,
    float* __restrict__ A1,
    const float* __restrict__ FV, _Float16* __restrict__ T)
{
    if (blockIdx.y < 4)
        gemm_body<true, false>(state, Q, A1, 1024, 1024, 1024,
                               blockIdx.x, blockIdx.y, 0);
    else
        transpose_body(FV, T, blockIdx.y - 4, blockIdx.x);
}

// ---------------------------------------------------------------------------
// Fused v7 (compile-fixed): the three proven-good axes COMBINED:
//  (1) b128 B-fragments from FV16T (R5: clean loads, FETCH 172 MB),
//  (2) barrier-free free-running K-loop (R3),
//  (3) >=3 waves/SIMD occupancy (R4's goal) via acc[4]: 512 threads =
//      8 wx-waves x 32 rows x 1024 cols, bt 0..7, 2048 blocks.
// R1-R6 localization: per-chunk time ~10-20x the BW+compute cost at
// 2 waves/SIMD in EVERY structure -> exposed load latency with no TLP.
// 64 AGPR + ~70 VGPR under bounds(512,3) -> 3-4 waves/SIMD.
// Drift-traffic guard (R2 lesson): FV16T[i] = 512 KB fp16 (8 i/XCD ~ 4 MB
// L2), and the whole 134 MB array is L3-resident -> drift re-reads hit L3,
// not HBM. A-operand: fp32 Mf rows, hi/lo split in-register.
// ---------------------------------------------------------------------------
__global__ __launch_bounds__(512, 3) void fused_attn_t16(
    const _Float16* __restrict__ T, const float* __restrict__ Mf,
    float* __restrict__ ctx, float* __restrict__ Wout)
{
    __shared__ __align__(16) float red1[32 * 8];
    __shared__ __align__(16) float red2[32 * 8];

    const int tid  = threadIdx.x;
    const int lane = tid & 63;
    const int wx   = tid >> 6;        // 0..7: d-slice (128 cols)
    const int l31 = lane & 31, l5 = lane >> 5;

    // XCD swizzle: all 8 bt of an i on one XCD, consecutive in dispatch.
    const int w   = blockIdx.x;       // 0..2047
    const int xcd = w & 7;
    const int k   = w >> 3;           // 0..255
    const int i   = (xcd << 5) + (k >> 3);  // 0..255
    const int bt  = k & 7;                  // 0..7

    const _Float16* __restrict__ Ti = T + (size_t)i * 1024 * 256;

    floatx16 acc[4];
#pragma unroll
    for (int nt = 0; nt < 4; ++nt)
#pragma unroll
        for (int j = 0; j < 16; ++j) acc[nt][j] = 0.0f;

    // A: row (m) = bt*32 + l31, k = ktg*32 + half*16 + l5*8 + j  (fp32 Mf)
    const int arow = bt * 32 + l31;
    const float* __restrict__ Ap = Mf + (size_t)arow * 256 + l5 * 8;
    // B: B[k][col] = FV[i][n=k][d=col] = Ti[col*256 + k]
    const _Float16* __restrict__ Bb = Ti + ((size_t)(wx * 128 + l31)) * 256 + l5 * 8;

#pragma unroll 1
    for (int ktg = 0; ktg < 8; ++ktg) {   // k = ktg*32 .. +32
        const float4 a00 = *(const float4*)(Ap + ktg * 32);
        const float4 a01 = *(const float4*)(Ap + ktg * 32 + 4);
        const float4 a10 = *(const float4*)(Ap + ktg * 32 + 16);
        const float4 a11 = *(const float4*)(Ap + ktg * 32 + 20);
        half8 b0[4], b1[4];
#pragma unroll
        for (int nt = 0; nt < 4; ++nt) {
            const _Float16* bp = Bb + (size_t)nt * 32 * 256 + ktg * 32;
            b0[nt] = *(const half8*)(bp);
            b1[nt] = *(const half8*)(bp + 16);
        }
        half8 a0h, a0l, a1h, a1l;
#pragma unroll
        for (int j = 0; j < 4; ++j) {
            _Float16 h, l;
            split_f32((&a00.x)[j], h, l); a0h[j] = h;     a0l[j] = l;
            split_f32((&a01.x)[j], h, l); a0h[4 + j] = h; a0l[4 + j] = l;
            split_f32((&a10.x)[j], h, l); a1h[j] = h;     a1l[j] = l;
            split_f32((&a11.x)[j], h, l); a1h[4 + j] = h; a1l[4 + j] = l;
        }
#pragma unroll
        for (int nt = 0; nt < 4; ++nt) {
            acc[nt] = __builtin_amdgcn_mfma_f32_32x32x16_f16(a0h, b0[nt], acc[nt], 0, 0, 0);
            acc[nt] = __builtin_amdgcn_mfma_f32_32x32x16_f16(a0l, b0[nt], acc[nt], 0, 0, 0);
        }
#pragma unroll
        for (int nt = 0; nt < 4; ++nt) {
            acc[nt] = __builtin_amdgcn_mfma_f32_32x32x16_f16(a1h, b1[nt], acc[nt], 0, 0, 0);
            acc[nt] = __builtin_amdgcn_mfma_f32_32x32x16_f16(a1l, b1[nt], acc[nt], 0, 0, 0);
        }
    }

    // ---- softmax over d (rows span 8 wx waves), per-reg fused reductions ----
    // lane holds: col = wx*128 + nt*32 + l31 ; row = (reg&3)+8*(reg>>2)+4*l5
#pragma unroll
    for (int reg = 0; reg < 16; ++reg) {
        float v = acc[0][reg];
#pragma unroll
        for (int nt = 1; nt < 4; ++nt) v = fmaxf(v, acc[nt][reg]);
#pragma unroll
        for (int off = 1; off < 32; off <<= 1) v = fmaxf(v, __shfl_xor(v, off));
        if (l31 == 0) {
            const int row = (reg & 3) + 8 * (reg >> 2) + 4 * l5;
            red1[row * 8 + wx] = v;
        }
    }
    __syncthreads();
#pragma unroll
    for (int reg = 0; reg < 16; ++reg) {
        const int row = (reg & 3) + 8 * (reg >> 2) + 4 * l5;
        const float4 a4 = *(const float4*)&red1[row * 8];
        const float4 b4 = *(const float4*)&red1[row * 8 + 4];
        const float rmax = fmaxf(fmaxf(fmaxf(a4.x, a4.y), fmaxf(a4.z, a4.w)),
                                 fmaxf(fmaxf(b4.x, b4.y), fmaxf(b4.z, b4.w)));
        float s = 0.0f;
#pragma unroll
        for (int nt = 0; nt < 4; ++nt) {
            const float p = __expf(acc[nt][reg] - rmax);
            acc[nt][reg] = p;
            s += p;
        }
#pragma unroll
        for (int off = 1; off < 32; off <<= 1) s += __shfl_xor(s, off);
        if (l31 == 0) red2[row * 8 + wx] = s;
    }
    __syncthreads();

    // ---- write W, accumulate context (FV from FV16T, L2-hot) ----
    float csum[4];
#pragma unroll
    for (int nt = 0; nt < 4; ++nt) csum[nt] = 0.0f;

    const int rowbase = bt * 32;
#pragma unroll
    for (int nt = 0; nt < 4; ++nt) {
        const int col = wx * 128 + nt * 32 + l31;
        const _Float16* fp = Ti + (size_t)col * 256 + rowbase + 4 * l5;
        half4 f[4];
#pragma unroll
        for (int g = 0; g < 4; ++g) f[g] = *(const half4*)(fp + 8 * g);
#pragma unroll
        for (int reg = 0; reg < 16; ++reg) {
            const int row = (reg & 3) + 8 * (reg >> 2) + 4 * l5;
            const float4 s4a = *(const float4*)&red2[row * 8];
            const float4 s4b = *(const float4*)&red2[row * 8 + 4];
            const float inv = 1.0f / (s4a.x + s4a.y + s4a.z + s4a.w +
                                      s4b.x + s4b.y + s4b.z + s4b.w);
            const float wv = acc[nt][reg] * inv;
            Wout[((size_t)(i * 256 + rowbase + row)) * 1024 + col] = wv;
            csum[nt] += wv * (float)f[reg >> 2][reg & 3];
        }
    }
#pragma unroll
    for (int nt = 0; nt < 4; ++nt) {
        const float v = csum[nt] + __shfl_xor(csum[nt], 32);
        if (l5 == 0)
            atomicAdd(&ctx[(size_t)i * 1024 + wx * 128 + nt * 32 + l31], v);
    }
}

// ---------------------------------------------------------------------------
extern "C" void kernel_launch(void* const* d_in, const int* in_sizes, int n_in,
                              void* d_out, int out_size, void* d_ws, size_t ws_size,
                              hipStream_t stream)
{
    const float* FV    = (const float*)d_in[0];  // [256,256,1024]
    const float* state = (const float*)d_in[1];  // [256,1024]
    const float* Q     = (const float*)d_in[2];  // [1024,1024]
    const float* Km    = (const float*)d_in[3];  // [1024,256]

    float* out = (float*)d_out;
    float* ctx = out;                 // [256,1024]
    float* W   = out + 256 * 1024;    // [256,256,1024]

    char* ws = (char*)d_ws;
    float*    A1 = (float*)ws;                               // [256,1024] fp32, 1 MB
    float*    Mf = (float*)(ws + (1 << 20));                 // [256,256]  fp32, 256 KB
    _Float16* T  = (_Float16*)(ws + (1 << 20) + (1 << 18));  // [256,1024,256] f16, 134 MB

    // split-K accumulator (Mf) + ctx atomics -> zero
    (void)hipMemsetAsync(Mf, 0, 1 << 18, stream);
    (void)hipMemsetAsync(ctx, 0, 256 * 1024 * sizeof(float), stream);

    // A1 = state @ Q^T concurrent with FV16T transpose
    gemm1_plus_transpose<<<dim3(16, 260), 256, 0, stream>>>(state, Q, A1, FV, T);

    // M = A1 @ K (B stored [K,N]), split-K x16 -> fp32 Mf
    gemm_splitk<false><<<dim3(4, 4, 16), 256, 0, stream>>>(
        A1, Km, Mf, 1024, 256, 64);

    // fused logits -> softmax -> W + ctx (barrier-free, acc[4], 3-4 waves/SIMD)
    fused_attn_t16<<<dim3(2048), 512, 0, stream>>>(T, Mf, ctx, W);
}

// Round 9
// 588.504 us; speedup vs baseline: 2.4198x; 2.4198x over previous
//
#include <hip/hip_runtime.h>

// Problem constants: B=N=256, D=S=1024
// out = [ctx 256*1024 fp32 ; W 256*256*1024 fp32]

typedef _Float16 half8 __attribute__((ext_vector_type(8)));
typedef float floatx16 __attribute__((ext_vector_type(16)));

static __device__ __forceinline__ void split_f32(float x, _Float16& hi, _Float16& lo) {
    _Float16 h = (_Float16)x;
    hi = h;
    lo = (_Float16)(x - (float)h);
}

// ---------------------------------------------------------------------------
// Split-K small GEMM (R6, proven): C[M,N] += A[M,K-slice] @ B, fp32 atomicAdd
// epilogue. Fills the machine for the small gemms (R6: saved ~70 us).
// fp32 in, hi/lo fp16 split on BOTH operands (3 MFMAs). Tile 64x64,
// 256 threads, BK=32. BT=true: B stored [N,K]; BT=false: B stored [K,N].
// ---------------------------------------------------------------------------
template <bool BT>
__global__ __launch_bounds__(256, 2) void gemm_splitk(
    const float* __restrict__ Ag, const float* __restrict__ Bg,
    float* __restrict__ Cf, int Kdim, int Ndim, int KC)
{
    __shared__ __align__(16) _Float16 AsHi[4 * 64 * 8];
    __shared__ __align__(16) _Float16 AsLo[4 * 64 * 8];
    __shared__ __align__(16) _Float16 BsHi[4 * 64 * 8];
    __shared__ __align__(16) _Float16 BsLo[4 * 64 * 8];

    const int tid  = threadIdx.x;
    const int lane = tid & 63;
    const int wave = tid >> 6;
    const int wy = wave >> 1, wx = wave & 1;
    const int l31 = lane & 31, l5 = lane >> 5;
    const int m0 = blockIdx.y * 64, n0 = blockIdx.x * 64;
    const int kt0 = (blockIdx.z * KC) >> 5;

    floatx16 acc;
#pragma unroll
    for (int j = 0; j < 16; ++j) acc[j] = 0.0f;

    const int sA_m  = tid >> 2;
    const int sA_kg = tid & 3;
    const int sB_n  = tid & 63;
    const int sB_kg = tid >> 6;

    const int nkt = KC / 32;
#pragma unroll 1
    for (int kt2 = 0; kt2 < nkt; ++kt2) {
        const int kt = kt0 + kt2;
        __syncthreads();
        {   // stage A chunk [32k x 64m] -> [kg][m][8] hi/lo
            const float* src = Ag + (size_t)(m0 + sA_m) * Kdim + kt * 32 + sA_kg * 8;
            half8 hi, lo;
#pragma unroll
            for (int j = 0; j < 8; ++j) {
                _Float16 h, l;
                split_f32(src[j], h, l);
                hi[j] = h; lo[j] = l;
            }
            *(half8*)&AsHi[(sA_kg * 64 + sA_m) * 8] = hi;
            *(half8*)&AsLo[(sA_kg * 64 + sA_m) * 8] = lo;
        }
        if constexpr (BT) {
            const float* src = Bg + (size_t)(n0 + sA_m) * Kdim + kt * 32 + sA_kg * 8;
            half8 hi, lo;
#pragma unroll
            for (int j = 0; j < 8; ++j) {
                _Float16 h, l;
                split_f32(src[j], h, l);
                hi[j] = h; lo[j] = l;
            }
            *(half8*)&BsHi[(sA_kg * 64 + sA_m) * 8] = hi;
            *(half8*)&BsLo[(sA_kg * 64 + sA_m) * 8] = lo;
        } else {
            const float* src = Bg + (size_t)(kt * 32 + sB_kg * 8) * Ndim + n0 + sB_n;
            half8 hi, lo;
#pragma unroll
            for (int j = 0; j < 8; ++j) {
                _Float16 h, l;
                split_f32(src[(size_t)j * Ndim], h, l);
                hi[j] = h; lo[j] = l;
            }
            *(half8*)&BsHi[(sB_kg * 64 + sB_n) * 8] = hi;
            *(half8*)&BsLo[(sB_kg * 64 + sB_n) * 8] = lo;
        }
        __syncthreads();
#pragma unroll
        for (int ks = 0; ks < 2; ++ks) {
            const int kg = ks * 2 + l5;
            const half8 ah = *(half8*)&AsHi[(kg * 64 + wy * 32 + l31) * 8];
            const half8 al = *(half8*)&AsLo[(kg * 64 + wy * 32 + l31) * 8];
            const half8 bh = *(half8*)&BsHi[(kg * 64 + wx * 32 + l31) * 8];
            const half8 bl = *(half8*)&BsLo[(kg * 64 + wx * 32 + l31) * 8];
            acc = __builtin_amdgcn_mfma_f32_32x32x16_f16(ah, bh, acc, 0, 0, 0);
            acc = __builtin_amdgcn_mfma_f32_32x32x16_f16(ah, bl, acc, 0, 0, 0);
            acc = __builtin_amdgcn_mfma_f32_32x32x16_f16(al, bh, acc, 0, 0, 0);
        }
    }

    // C/D layout (verified): col = lane&31, row = (reg&3) + 8*(reg>>2) + 4*(lane>>5)
#pragma unroll
    for (int reg = 0; reg < 16; ++reg) {
        const int row = m0 + wy * 32 + (reg & 3) + 8 * (reg >> 2) + 4 * l5;
        const int col = n0 + wx * 32 + l31;
        atomicAdd(&Cf[(size_t)row * Ndim + col], acc[reg]);
    }
}

// Swizzled byte offset into Bs: spreads d-stride-4-per-lane writes across
// banks. Involution (XOR of bits [6:4] with bits [9:7]); applied identically
// on store and fragment-read, so placement is consistent by construction.
static __device__ __forceinline__ int bs_swz(int byte_off) {
    return byte_off ^ (((byte_off >> 7) & 7) << 4);
}

// ---------------------------------------------------------------------------
// Fused (R6 structure, best measured 283 us) with ONE change: B-staging is
// 8x float4 loads per thread (wave = contiguous 1 KB per instruction) +
// in-register 8x4 transpose, replacing 32 scalar stride-1024 dword loads.
// Cuts per-chunk VMEM instructions ~4x (theory: the 270 us floor is VMEM
// issue/latency, not BW -- R2/R8 sustained 2.4-2.75 TB/s vs our 2.0).
// Everything else identical to R6: 64 rows x 1024 d per block, 8 waves,
// acc[8], 1024 blocks, XCD swizzle (4 lockstep siblings/i on one XCD,
// proven FETCH ~= unique FV), fp32 M with in-register hi/lo split.
// ---------------------------------------------------------------------------
__global__ __launch_bounds__(512, 2) void fused_attn(
    const float* __restrict__ FV, const float* __restrict__ Mf,
    float* __restrict__ ctx, float* __restrict__ Wout)
{
    __shared__ __align__(16) _Float16 AsHi[2 * 64 * 8];
    __shared__ __align__(16) _Float16 AsLo[2 * 64 * 8];
    __shared__ __align__(16) _Float16 Bs[2 * 1024 * 8];
    __shared__ __align__(16) float red1[64 * 4];
    __shared__ __align__(16) float red2[64 * 4];

    const int tid  = threadIdx.x;
    const int lane = tid & 63;
    const int wave = tid >> 6;
    const int wx = wave & 3;   // d-slice (256 cols)
    const int wy = wave >> 2;  // m-half (32 rows)
    const int l31 = lane & 31, l5 = lane >> 5;

    // XCD-aware swizzle: all 4 bt of an i share one XCD.
    const int w   = blockIdx.x;   // 0..1023
    const int xcd = w & 7;
    const int k   = w >> 3;       // 0..127
    const int i   = (xcd << 5) + (k >> 2);  // 0..255
    const int bt  = k & 3;                  // 0..3

    const float* __restrict__ FVi = FV + (size_t)i * 256 * 1024;

    floatx16 acc[8];
#pragma unroll
    for (int nt = 0; nt < 8; ++nt)
#pragma unroll
        for (int j = 0; j < 16; ++j) acc[nt][j] = 0.0f;

    const int am = tid >> 1, akg = tid & 1;  // A staging (tid < 128)

    // B staging mapping: thread owns n-subgroup n8 = tid>>8 (8 rows) and
    // cols [c0, c0+4), c0 = (tid&255)*4. 8x float4 per chunk.
    const int n8 = tid >> 8;
    const int c0 = (tid & 255) * 4;

    // ---- prefetch chunk 0 into registers ----
    float4 pv4[8];
    float4 pa0, pa1;
    {
        const float* src = FVi + (size_t)(n8 * 8) * 1024 + c0;
#pragma unroll
        for (int r = 0; r < 8; ++r) pv4[r] = *(const float4*)(src + (size_t)r * 1024);
    }
    if (tid < 128) {
        const float* ap = Mf + (size_t)(bt * 64 + am) * 256 + akg * 8;
        pa0 = *(const float4*)(ap);
        pa1 = *(const float4*)(ap + 4);
    }

#pragma unroll 1
    for (int kt = 0; kt < 16; ++kt) {
        __syncthreads();  // drains prefetch (issued a full compute-phase ago)
        // ---- store staged chunk to LDS (fp32 M split to hi/lo here) ----
        if (tid < 128) {
            half8 hi, lo;
#pragma unroll
            for (int j = 0; j < 4; ++j) {
                _Float16 h, l;
                split_f32((&pa0.x)[j], h, l);
                hi[j] = h; lo[j] = l;
            }
#pragma unroll
            for (int j = 0; j < 4; ++j) {
                _Float16 h, l;
                split_f32((&pa1.x)[j], h, l);
                hi[4 + j] = h; lo[4 + j] = l;
            }
            *(half8*)&AsHi[(akg * 64 + am) * 8] = hi;
            *(half8*)&AsLo[(akg * 64 + am) * 8] = lo;
        }
        // B: in-register 8x4 transpose -> 4 half8 stores (swizzled banks)
#pragma unroll
        for (int j = 0; j < 4; ++j) {
            half8 h;
#pragma unroll
            for (int r = 0; r < 8; ++r) h[r] = (_Float16)((&pv4[r].x)[j]);
            const int byte_off = (n8 * 1024 + c0 + j) * 16;
            *(half8*)((char*)Bs + bs_swz(byte_off)) = h;
        }
        __syncthreads();
        // ---- prefetch next chunk (overlaps with compute below) ----
        if (kt + 1 < 16) {
            const float* src = FVi + (size_t)((kt + 1) * 16 + n8 * 8) * 1024 + c0;
#pragma unroll
            for (int r = 0; r < 8; ++r) pv4[r] = *(const float4*)(src + (size_t)r * 1024);
            if (tid < 128) {
                const float* ap = Mf + (size_t)(bt * 64 + am) * 256 + (kt + 1) * 16 + akg * 8;
                pa0 = *(const float4*)(ap);
                pa1 = *(const float4*)(ap + 4);
            }
        }
        // ---- compute: 8 n-tiles x (hi,lo) MFMA ----
        const half8 ah = *(half8*)&AsHi[(l5 * 64 + wy * 32 + l31) * 8];
        const half8 al = *(half8*)&AsLo[(l5 * 64 + wy * 32 + l31) * 8];
#pragma unroll
        for (int nt = 0; nt < 8; ++nt) {
            const int byte_off = (l5 * 1024 + wx * 256 + nt * 32 + l31) * 16;
            const half8 b = *(const half8*)((const char*)Bs + bs_swz(byte_off));
            acc[nt] = __builtin_amdgcn_mfma_f32_32x32x16_f16(ah, b, acc[nt], 0, 0, 0);
            acc[nt] = __builtin_amdgcn_mfma_f32_32x32x16_f16(al, b, acc[nt], 0, 0, 0);
        }
    }

    // ---- softmax over d (rows span 4 wx waves) ----
    // lane holds: col = wx*256 + nt*32 + l31 ; row = wy*32 + (reg&3)+8*(reg>>2)+4*l5
    float st[16];
#pragma unroll
    for (int reg = 0; reg < 16; ++reg) {
        float v = acc[0][reg];
#pragma unroll
        for (int nt = 1; nt < 8; ++nt) v = fmaxf(v, acc[nt][reg]);
#pragma unroll
        for (int off = 1; off < 32; off <<= 1) v = fmaxf(v, __shfl_xor(v, off));
        st[reg] = v;
    }
    if (l31 == 0) {
#pragma unroll
        for (int reg = 0; reg < 16; ++reg) {
            const int row = wy * 32 + (reg & 3) + 8 * (reg >> 2) + 4 * l5;
            red1[row * 4 + wx] = st[reg];
        }
    }
    __syncthreads();
    float rmax[16];
#pragma unroll
    for (int reg = 0; reg < 16; ++reg) {
        const int row = wy * 32 + (reg & 3) + 8 * (reg >> 2) + 4 * l5;
        const float4 m4 = *(const float4*)&red1[row * 4];
        rmax[reg] = fmaxf(fmaxf(m4.x, m4.y), fmaxf(m4.z, m4.w));
    }
#pragma unroll
    for (int reg = 0; reg < 16; ++reg) {
        float s = 0.0f;
#pragma unroll
        for (int nt = 0; nt < 8; ++nt) {
            const float p = __expf(acc[nt][reg] - rmax[reg]);
            acc[nt][reg] = p;
            s += p;
        }
#pragma unroll
        for (int off = 1; off < 32; off <<= 1) s += __shfl_xor(s, off);
        st[reg] = s;
    }
    if (l31 == 0) {
#pragma unroll
        for (int reg = 0; reg < 16; ++reg) {
            const int row = wy * 32 + (reg & 3) + 8 * (reg >> 2) + 4 * l5;
            red2[row * 4 + wx] = st[reg];
        }
    }
    __syncthreads();
    float inv[16];
#pragma unroll
    for (int reg = 0; reg < 16; ++reg) {
        const int row = wy * 32 + (reg & 3) + 8 * (reg >> 2) + 4 * l5;
        const float4 s4 = *(const float4*)&red2[row * 4];
        inv[reg] = 1.0f / (s4.x + s4.y + s4.z + s4.w);
    }

    // ---- write W, accumulate context ----
    float csum[8];
#pragma unroll
    for (int nt = 0; nt < 8; ++nt) csum[nt] = 0.0f;

    const int rowbase = bt * 64 + wy * 32;
#pragma unroll
    for (int nt = 0; nt < 8; ++nt) {
        const int col = wx * 256 + nt * 32 + l31;
#pragma unroll
        for (int reg = 0; reg < 16; ++reg) {
            const int row = (reg & 3) + 8 * (reg >> 2) + 4 * l5;
            const float wv = acc[nt][reg] * inv[reg];
            Wout[((size_t)(i * 256 + rowbase + row)) * 1024 + col] = wv;
            const float fv = FVi[(size_t)(rowbase + row) * 1024 + col];
            csum[nt] += wv * fv;
        }
    }
#pragma unroll
    for (int nt = 0; nt < 8; ++nt) {
        const float v = csum[nt] + __shfl_xor(csum[nt], 32);
        if (l5 == 0)
            atomicAdd(&ctx[(size_t)i * 1024 + wx * 256 + nt * 32 + l31], v);
    }
}

// ---------------------------------------------------------------------------
extern "C" void kernel_launch(void* const* d_in, const int* in_sizes, int n_in,
                              void* d_out, int out_size, void* d_ws, size_t ws_size,
                              hipStream_t stream)
{
    const float* FV    = (const float*)d_in[0];  // [256,256,1024]
    const float* state = (const float*)d_in[1];  // [256,1024]
    const float* Q     = (const float*)d_in[2];  // [1024,1024]
    const float* Km    = (const float*)d_in[3];  // [1024,256]

    float* out = (float*)d_out;
    float* ctx = out;                 // [256,1024]
    float* W   = out + 256 * 1024;    // [256,256,1024]

    char* ws = (char*)d_ws;
    float* A1 = (float*)ws;               // [256,1024] fp32, 1 MB
    float* Mf = (float*)(ws + (1 << 20)); // [256,256]  fp32, 256 KB

    // split-K accumulators + ctx atomics -> zero them
    (void)hipMemsetAsync(ws, 0, (1 << 20) + (1 << 18), stream);
    (void)hipMemsetAsync(ctx, 0, 256 * 1024 * sizeof(float), stream);

    // A1 = state @ Q^T   (B stored [N,K]: Q[s,t], contract t), split-K x8
    gemm_splitk<true><<<dim3(16, 4, 8), 256, 0, stream>>>(
        state, Q, A1, 1024, 1024, 128);

    // M = A1 @ K  (B stored [K,N]), split-K x16
    gemm_splitk<false><<<dim3(4, 4, 16), 256, 0, stream>>>(
        A1, Km, Mf, 1024, 256, 64);

    // fused logits -> softmax -> W + ctx (R6 structure, float4 staging)
    fused_attn<<<dim3(1024), 512, 0, stream>>>(FV, Mf, ctx, W);
}

// Round 10
// 585.694 us; speedup vs baseline: 2.4314x; 1.0048x over previous
//
#include <hip/hip_runtime.h>

// Problem constants: B=N=256, D=S=1024
// out = [ctx 256*1024 fp32 ; W 256*256*1024 fp32]

typedef _Float16 half8 __attribute__((ext_vector_type(8)));
typedef _Float16 half4 __attribute__((ext_vector_type(4)));
typedef float floatx16 __attribute__((ext_vector_type(16)));

static __device__ __forceinline__ void split_f32(float x, _Float16& hi, _Float16& lo) {
    _Float16 h = (_Float16)x;
    hi = h;
    lo = (_Float16)(x - (float)h);
}

// ---------------------------------------------------------------------------
// Split-K small GEMM (R6, proven): C[M,N] += A[M,K-slice] @ B, fp32 atomicAdd
// epilogue. fp32 in, hi/lo fp16 split on BOTH operands (3 MFMAs).
// Tile 64x64, 256 threads, BK=32.
// ---------------------------------------------------------------------------
template <bool BT>
__global__ __launch_bounds__(256, 2) void gemm_splitk(
    const float* __restrict__ Ag, const float* __restrict__ Bg,
    float* __restrict__ Cf, int Kdim, int Ndim, int KC)
{
    __shared__ __align__(16) _Float16 AsHi[4 * 64 * 8];
    __shared__ __align__(16) _Float16 AsLo[4 * 64 * 8];
    __shared__ __align__(16) _Float16 BsHi[4 * 64 * 8];
    __shared__ __align__(16) _Float16 BsLo[4 * 64 * 8];

    const int tid  = threadIdx.x;
    const int lane = tid & 63;
    const int wave = tid >> 6;
    const int wy = wave >> 1, wx = wave & 1;
    const int l31 = lane & 31, l5 = lane >> 5;
    const int m0 = blockIdx.y * 64, n0 = blockIdx.x * 64;
    const int kt0 = (blockIdx.z * KC) >> 5;

    floatx16 acc;
#pragma unroll
    for (int j = 0; j < 16; ++j) acc[j] = 0.0f;

    const int sA_m  = tid >> 2;
    const int sA_kg = tid & 3;
    const int sB_n  = tid & 63;
    const int sB_kg = tid >> 6;

    const int nkt = KC / 32;
#pragma unroll 1
    for (int kt2 = 0; kt2 < nkt; ++kt2) {
        const int kt = kt0 + kt2;
        __syncthreads();
        {
            const float* src = Ag + (size_t)(m0 + sA_m) * Kdim + kt * 32 + sA_kg * 8;
            half8 hi, lo;
#pragma unroll
            for (int j = 0; j < 8; ++j) {
                _Float16 h, l;
                split_f32(src[j], h, l);
                hi[j] = h; lo[j] = l;
            }
            *(half8*)&AsHi[(sA_kg * 64 + sA_m) * 8] = hi;
            *(half8*)&AsLo[(sA_kg * 64 + sA_m) * 8] = lo;
        }
        if constexpr (BT) {
            const float* src = Bg + (size_t)(n0 + sA_m) * Kdim + kt * 32 + sA_kg * 8;
            half8 hi, lo;
#pragma unroll
            for (int j = 0; j < 8; ++j) {
                _Float16 h, l;
                split_f32(src[j], h, l);
                hi[j] = h; lo[j] = l;
            }
            *(half8*)&BsHi[(sA_kg * 64 + sA_m) * 8] = hi;
            *(half8*)&BsLo[(sA_kg * 64 + sA_m) * 8] = lo;
        } else {
            const float* src = Bg + (size_t)(kt * 32 + sB_kg * 8) * Ndim + n0 + sB_n;
            half8 hi, lo;
#pragma unroll
            for (int j = 0; j < 8; ++j) {
                _Float16 h, l;
                split_f32(src[(size_t)j * Ndim], h, l);
                hi[j] = h; lo[j] = l;
            }
            *(half8*)&BsHi[(sB_kg * 64 + sB_n) * 8] = hi;
            *(half8*)&BsLo[(sB_kg * 64 + sB_n) * 8] = lo;
        }
        __syncthreads();
#pragma unroll
        for (int ks = 0; ks < 2; ++ks) {
            const int kg = ks * 2 + l5;
            const half8 ah = *(half8*)&AsHi[(kg * 64 + wy * 32 + l31) * 8];
            const half8 al = *(half8*)&AsLo[(kg * 64 + wy * 32 + l31) * 8];
            const half8 bh = *(half8*)&BsHi[(kg * 64 + wx * 32 + l31) * 8];
            const half8 bl = *(half8*)&BsLo[(kg * 64 + wx * 32 + l31) * 8];
            acc = __builtin_amdgcn_mfma_f32_32x32x16_f16(ah, bh, acc, 0, 0, 0);
            acc = __builtin_amdgcn_mfma_f32_32x32x16_f16(ah, bl, acc, 0, 0, 0);
            acc = __builtin_amdgcn_mfma_f32_32x32x16_f16(al, bh, acc, 0, 0, 0);
        }
    }

    // C/D layout (verified): col = lane&31, row = (reg&3) + 8*(reg>>2) + 4*(lane>>5)
#pragma unroll
    for (int reg = 0; reg < 16; ++reg) {
        const int row = m0 + wy * 32 + (reg & 3) + 8 * (reg >> 2) + 4 * l5;
        const int col = n0 + wx * 32 + l31;
        atomicAdd(&Cf[(size_t)row * Ndim + col], acc[reg]);
    }
}

// Bank swizzle for Bs (proven R9): XOR bits[6:4] with bits[9:7]. Involution;
// applied identically on store and read, so placement is self-consistent.
static __device__ __forceinline__ int bs_swz(int byte_off) {
    return byte_off ^ (((byte_off >> 7) & 7) << 4);
}

// ---------------------------------------------------------------------------
// Fused R10 = R4 geometry x R9 staging:
//  - 1024 threads = 16 waves (2 wy x 8 wx), acc[4] = 64 AGPR, bounds(1024,4)
//    -> 4 waves/SIMD (R4 measured 45.5% occupancy, VGPR=64 with a BIGGER
//    32-reg scalar prefetch; float4 prefetch needs only 16 regs).
//  - float4 B-staging (R9: -28 us at 8 waves): 4 float4/thread, in-register
//    4x4 transpose, b64 LDS stores via bs_swz.
//  - Same 1024-block grid, XCD swizzle, barriers, per-reg fused softmax (R4).
// Theory: 255 us floor = stall/convoy exposure at 2 waves/SIMD; R4's earlier
// regression at 4 waves was its 32-scalar-VMEM/thread/chunk issue storm
// (fixed here). Traffic pattern bit-identical to R9's verified 259 MB.
// ---------------------------------------------------------------------------
__global__ __launch_bounds__(1024, 4) void fused_attn(
    const float* __restrict__ FV, const float* __restrict__ Mf,
    float* __restrict__ ctx, float* __restrict__ Wout)
{
    __shared__ __align__(16) _Float16 AsHi[2 * 64 * 8];
    __shared__ __align__(16) _Float16 AsLo[2 * 64 * 8];
    __shared__ __align__(16) _Float16 Bs[2 * 1024 * 8];
    __shared__ __align__(16) float red1[64 * 8];
    __shared__ __align__(16) float red2[64 * 8];

    const int tid  = threadIdx.x;
    const int lane = tid & 63;
    const int wave = tid >> 6;          // 0..15
    const int wx = wave & 7;            // d-slice (128 cols)
    const int wy = wave >> 3;           // m-half (32 rows)
    const int l31 = lane & 31, l5 = lane >> 5;

    // XCD-aware swizzle: all 4 bt of an i share one XCD (proven map).
    const int w   = blockIdx.x;   // 0..1023
    const int xcd = w & 7;
    const int k   = w >> 3;       // 0..127
    const int i   = (xcd << 5) + (k >> 2);  // 0..255
    const int bt  = k & 3;                  // 0..3

    const float* __restrict__ FVi = FV + (size_t)i * 256 * 1024;

    floatx16 acc[4];
#pragma unroll
    for (int nt = 0; nt < 4; ++nt)
#pragma unroll
        for (int j = 0; j < 16; ++j) acc[nt][j] = 0.0f;

    const int am = tid >> 1, akg = tid & 1;  // A staging (tid < 128)

    // B staging: thread owns n-group ng = tid>>8 (4 rows) and d-quad
    // dq = tid & 255 (cols dq*4..+4). 4 float4 loads per chunk.
    const int ng = tid >> 8;        // 0..3
    const int dq = tid & 255;       // 0..255

    // ---- prefetch chunk 0 ----
    float4 pv[4];
    float4 pa0, pa1;
#pragma unroll
    for (int r = 0; r < 4; ++r)
        pv[r] = *(const float4*)(FVi + (size_t)(ng * 4 + r) * 1024 + dq * 4);
    if (tid < 128) {
        const float* ap = Mf + (size_t)(bt * 64 + am) * 256 + akg * 8;
        pa0 = *(const float4*)(ap);
        pa1 = *(const float4*)(ap + 4);
    }

#pragma unroll 1
    for (int kt = 0; kt < 16; ++kt) {
        __syncthreads();  // drains prefetch (issued a full compute-phase ago)
        // ---- A: fp32 M split to hi/lo, store to LDS ----
        if (tid < 128) {
            half8 hi, lo;
#pragma unroll
            for (int j = 0; j < 4; ++j) {
                _Float16 h, l;
                split_f32((&pa0.x)[j], h, l);
                hi[j] = h; lo[j] = l;
            }
#pragma unroll
            for (int j = 0; j < 4; ++j) {
                _Float16 h, l;
                split_f32((&pa1.x)[j], h, l);
                hi[4 + j] = h; lo[4 + j] = l;
            }
            *(half8*)&AsHi[(akg * 64 + am) * 8] = hi;
            *(half8*)&AsLo[(akg * 64 + am) * 8] = lo;
        }
        // ---- B: in-register 4x4 transpose -> 4 b64 stores (swizzled) ----
        // Granule (no*1024 + d) holds n = no*8..+8 at column d; this thread
        // contributes rows ng*4..+4 = half-granule at byte offset (ng&1)*8.
#pragma unroll
        for (int j = 0; j < 4; ++j) {
            half4 h;
#pragma unroll
            for (int r = 0; r < 4; ++r) h[r] = (_Float16)((&pv[r].x)[j]);
            const int byte_off = ((ng >> 1) * 1024 + dq * 4 + j) * 16 + (ng & 1) * 8;
            *(half4*)((char*)Bs + bs_swz(byte_off)) = h;
        }
        __syncthreads();
        // ---- prefetch next chunk (overlaps with compute below) ----
        if (kt + 1 < 16) {
#pragma unroll
            for (int r = 0; r < 4; ++r)
                pv[r] = *(const float4*)(FVi + (size_t)((kt + 1) * 16 + ng * 4 + r) * 1024 + dq * 4);
            if (tid < 128) {
                const float* ap = Mf + (size_t)(bt * 64 + am) * 256 + (kt + 1) * 16 + akg * 8;
                pa0 = *(const float4*)(ap);
                pa1 = *(const float4*)(ap + 4);
            }
        }
        // ---- compute: 4 n-tiles x (hi,lo) MFMA ----
        const half8 ah = *(half8*)&AsHi[(l5 * 64 + wy * 32 + l31) * 8];
        const half8 al = *(half8*)&AsLo[(l5 * 64 + wy * 32 + l31) * 8];
#pragma unroll
        for (int nt = 0; nt < 4; ++nt) {
            const int byte_off = (l5 * 1024 + wx * 128 + nt * 32 + l31) * 16;
            const half8 b = *(const half8*)((const char*)Bs + bs_swz(byte_off));
            acc[nt] = __builtin_amdgcn_mfma_f32_32x32x16_f16(ah, b, acc[nt], 0, 0, 0);
            acc[nt] = __builtin_amdgcn_mfma_f32_32x32x16_f16(al, b, acc[nt], 0, 0, 0);
        }
    }

    // ---- softmax over d (rows span 8 wx waves), per-reg fused (R4) ----
    // lane holds: col = wx*128 + nt*32 + l31 ; row = wy*32 + (reg&3)+8*(reg>>2)+4*l5
#pragma unroll
    for (int reg = 0; reg < 16; ++reg) {
        float v = acc[0][reg];
#pragma unroll
        for (int nt = 1; nt < 4; ++nt) v = fmaxf(v, acc[nt][reg]);
#pragma unroll
        for (int off = 1; off < 32; off <<= 1) v = fmaxf(v, __shfl_xor(v, off));
        if (l31 == 0) {
            const int row = wy * 32 + (reg & 3) + 8 * (reg >> 2) + 4 * l5;
            red1[row * 8 + wx] = v;
        }
    }
    __syncthreads();
#pragma unroll
    for (int reg = 0; reg < 16; ++reg) {
        const int row = wy * 32 + (reg & 3) + 8 * (reg >> 2) + 4 * l5;
        const float4 a4 = *(const float4*)&red1[row * 8];
        const float4 b4 = *(const float4*)&red1[row * 8 + 4];
        const float rmax = fmaxf(fmaxf(fmaxf(a4.x, a4.y), fmaxf(a4.z, a4.w)),
                                 fmaxf(fmaxf(b4.x, b4.y), fmaxf(b4.z, b4.w)));
        float s = 0.0f;
#pragma unroll
        for (int nt = 0; nt < 4; ++nt) {
            const float p = __expf(acc[nt][reg] - rmax);
            acc[nt][reg] = p;
            s += p;
        }
#pragma unroll
        for (int off = 1; off < 32; off <<= 1) s += __shfl_xor(s, off);
        if (l31 == 0) red2[row * 8 + wx] = s;
    }
    __syncthreads();

    // ---- write W, accumulate context ----
    float csum[4];
#pragma unroll
    for (int nt = 0; nt < 4; ++nt) csum[nt] = 0.0f;

    const int rowbase = bt * 64 + wy * 32;
#pragma unroll
    for (int reg = 0; reg < 16; ++reg) {
        const int row = (reg & 3) + 8 * (reg >> 2) + 4 * l5;
        const float4 a4 = *(const float4*)&red2[(wy * 32 + row) * 8];
        const float4 b4 = *(const float4*)&red2[(wy * 32 + row) * 8 + 4];
        const float inv = 1.0f / (a4.x + a4.y + a4.z + a4.w + b4.x + b4.y + b4.z + b4.w);
#pragma unroll
        for (int nt = 0; nt < 4; ++nt) {
            const int col = wx * 128 + nt * 32 + l31;
            const float wv = acc[nt][reg] * inv;
            Wout[((size_t)(i * 256 + rowbase + row)) * 1024 + col] = wv;
            const float fv = FVi[(size_t)(rowbase + row) * 1024 + col];
            csum[nt] += wv * fv;
        }
    }
#pragma unroll
    for (int nt = 0; nt < 4; ++nt) {
        const float v = csum[nt] + __shfl_xor(csum[nt], 32);
        if (l5 == 0)
            atomicAdd(&ctx[(size_t)i * 1024 + wx * 128 + nt * 32 + l31], v);
    }
}

// ---------------------------------------------------------------------------
extern "C" void kernel_launch(void* const* d_in, const int* in_sizes, int n_in,
                              void* d_out, int out_size, void* d_ws, size_t ws_size,
                              hipStream_t stream)
{
    const float* FV    = (const float*)d_in[0];  // [256,256,1024]
    const float* state = (const float*)d_in[1];  // [256,1024]
    const float* Q     = (const float*)d_in[2];  // [1024,1024]
    const float* Km    = (const float*)d_in[3];  // [1024,256]

    float* out = (float*)d_out;
    float* ctx = out;                 // [256,1024]
    float* W   = out + 256 * 1024;    // [256,256,1024]

    char* ws = (char*)d_ws;
    float* A1 = (float*)ws;               // [256,1024] fp32, 1 MB
    float* Mf = (float*)(ws + (1 << 20)); // [256,256]  fp32, 256 KB

    // split-K accumulators + ctx atomics -> zero them
    (void)hipMemsetAsync(ws, 0, (1 << 20) + (1 << 18), stream);
    (void)hipMemsetAsync(ctx, 0, 256 * 1024 * sizeof(float), stream);

    // A1 = state @ Q^T   (B stored [N,K]: Q[s,t], contract t), split-K x8
    gemm_splitk<true><<<dim3(16, 4, 8), 256, 0, stream>>>(
        state, Q, A1, 1024, 1024, 128);

    // M = A1 @ K  (B stored [K,N]), split-K x16
    gemm_splitk<false><<<dim3(4, 4, 16), 256, 0, stream>>>(
        A1, Km, Mf, 1024, 256, 64);

    // fused logits -> softmax -> W + ctx (16 waves, float4 staging)
    fused_attn<<<dim3(1024), 1024, 0, stream>>>(FV, Mf, ctx, W);
}

// Round 11
// 583.081 us; speedup vs baseline: 2.4423x; 1.0045x over previous
//
#include <hip/hip_runtime.h>

// Problem constants: B=N=256, D=S=1024
// out = [ctx 256*1024 fp32 ; W 256*256*1024 fp32]

typedef _Float16 half8 __attribute__((ext_vector_type(8)));
typedef float floatx16 __attribute__((ext_vector_type(16)));

static __device__ __forceinline__ void split_f32(float x, _Float16& hi, _Float16& lo) {
    _Float16 h = (_Float16)x;
    hi = h;
    lo = (_Float16)(x - (float)h);
}

// ---------------------------------------------------------------------------
// Split-K small GEMM (R6, proven): C[M,N] += A[M,K-slice] @ B, fp32 atomicAdd
// epilogue. fp32 in, hi/lo fp16 split on BOTH operands (3 MFMAs).
// Tile 64x64, 256 threads, BK=32.
// ---------------------------------------------------------------------------
template <bool BT>
__global__ __launch_bounds__(256, 2) void gemm_splitk(
    const float* __restrict__ Ag, const float* __restrict__ Bg,
    float* __restrict__ Cf, int Kdim, int Ndim, int KC)
{
    __shared__ __align__(16) _Float16 AsHi[4 * 64 * 8];
    __shared__ __align__(16) _Float16 AsLo[4 * 64 * 8];
    __shared__ __align__(16) _Float16 BsHi[4 * 64 * 8];
    __shared__ __align__(16) _Float16 BsLo[4 * 64 * 8];

    const int tid  = threadIdx.x;
    const int lane = tid & 63;
    const int wave = tid >> 6;
    const int wy = wave >> 1, wx = wave & 1;
    const int l31 = lane & 31, l5 = lane >> 5;
    const int m0 = blockIdx.y * 64, n0 = blockIdx.x * 64;
    const int kt0 = (blockIdx.z * KC) >> 5;

    floatx16 acc;
#pragma unroll
    for (int j = 0; j < 16; ++j) acc[j] = 0.0f;

    const int sA_m  = tid >> 2;
    const int sA_kg = tid & 3;
    const int sB_n  = tid & 63;
    const int sB_kg = tid >> 6;

    const int nkt = KC / 32;
#pragma unroll 1
    for (int kt2 = 0; kt2 < nkt; ++kt2) {
        const int kt = kt0 + kt2;
        __syncthreads();
        {
            const float* src = Ag + (size_t)(m0 + sA_m) * Kdim + kt * 32 + sA_kg * 8;
            half8 hi, lo;
#pragma unroll
            for (int j = 0; j < 8; ++j) {
                _Float16 h, l;
                split_f32(src[j], h, l);
                hi[j] = h; lo[j] = l;
            }
            *(half8*)&AsHi[(sA_kg * 64 + sA_m) * 8] = hi;
            *(half8*)&AsLo[(sA_kg * 64 + sA_m) * 8] = lo;
        }
        if constexpr (BT) {
            const float* src = Bg + (size_t)(n0 + sA_m) * Kdim + kt * 32 + sA_kg * 8;
            half8 hi, lo;
#pragma unroll
            for (int j = 0; j < 8; ++j) {
                _Float16 h, l;
                split_f32(src[j], h, l);
                hi[j] = h; lo[j] = l;
            }
            *(half8*)&BsHi[(sA_kg * 64 + sA_m) * 8] = hi;
            *(half8*)&BsLo[(sA_kg * 64 + sA_m) * 8] = lo;
        } else {
            const float* src = Bg + (size_t)(kt * 32 + sB_kg * 8) * Ndim + n0 + sB_n;
            half8 hi, lo;
#pragma unroll
            for (int j = 0; j < 8; ++j) {
                _Float16 h, l;
                split_f32(src[(size_t)j * Ndim], h, l);
                hi[j] = h; lo[j] = l;
            }
            *(half8*)&BsHi[(sB_kg * 64 + sB_n) * 8] = hi;
            *(half8*)&BsLo[(sB_kg * 64 + sB_n) * 8] = lo;
        }
        __syncthreads();
#pragma unroll
        for (int ks = 0; ks < 2; ++ks) {
            const int kg = ks * 2 + l5;
            const half8 ah = *(half8*)&AsHi[(kg * 64 + wy * 32 + l31) * 8];
            const half8 al = *(half8*)&AsLo[(kg * 64 + wy * 32 + l31) * 8];
            const half8 bh = *(half8*)&BsHi[(kg * 64 + wx * 32 + l31) * 8];
            const half8 bl = *(half8*)&BsLo[(kg * 64 + wx * 32 + l31) * 8];
            acc = __builtin_amdgcn_mfma_f32_32x32x16_f16(ah, bh, acc, 0, 0, 0);
            acc = __builtin_amdgcn_mfma_f32_32x32x16_f16(ah, bl, acc, 0, 0, 0);
            acc = __builtin_amdgcn_mfma_f32_32x32x16_f16(al, bh, acc, 0, 0, 0);
        }
    }

    // C/D layout (verified): col = lane&31, row = (reg&3) + 8*(reg>>2) + 4*(lane>>5)
#pragma unroll
    for (int reg = 0; reg < 16; ++reg) {
        const int row = m0 + wy * 32 + (reg & 3) + 8 * (reg >> 2) + 4 * l5;
        const int col = n0 + wx * 32 + l31;
        atomicAdd(&Cf[(size_t)row * Ndim + col], acc[reg]);
    }
}

// Bank swizzle for Bs (proven R9): XOR bits[6:4] with bits[9:7]. Involution;
// applied identically on store and read, so placement is self-consistent.
static __device__ __forceinline__ int bs_swz(int byte_off) {
    return byte_off ^ (((byte_off >> 7) & 7) << 4);
}

// ---------------------------------------------------------------------------
// Fused R11 = R9 (best, 255 us) + NON-TEMPORAL W stores.
// R10 falsified occupancy for the third time (4 waves/SIMD, clean traffic,
// 272 us). Revised model: the lockstep structure phase-segregates memory --
// all blocks run the read-only K-loop together (write path idle), then all
// drain 268 MB of W together (read path idle): T ~ T_read + T_write.
// W is write-once, never re-read: nt stores keep L2 read-clean (FV window
// stays resident for staging multicast + epilogue re-read) and shorten the
// epilogue drain. Everything else bit-identical to R9.
// ---------------------------------------------------------------------------
__global__ __launch_bounds__(512, 2) void fused_attn(
    const float* __restrict__ FV, const float* __restrict__ Mf,
    float* __restrict__ ctx, float* __restrict__ Wout)
{
    __shared__ __align__(16) _Float16 AsHi[2 * 64 * 8];
    __shared__ __align__(16) _Float16 AsLo[2 * 64 * 8];
    __shared__ __align__(16) _Float16 Bs[2 * 1024 * 8];
    __shared__ __align__(16) float red1[64 * 4];
    __shared__ __align__(16) float red2[64 * 4];

    const int tid  = threadIdx.x;
    const int lane = tid & 63;
    const int wave = tid >> 6;
    const int wx = wave & 3;   // d-slice (256 cols)
    const int wy = wave >> 2;  // m-half (32 rows)
    const int l31 = lane & 31, l5 = lane >> 5;

    // XCD-aware swizzle: all 4 bt of an i share one XCD.
    const int w   = blockIdx.x;   // 0..1023
    const int xcd = w & 7;
    const int k   = w >> 3;       // 0..127
    const int i   = (xcd << 5) + (k >> 2);  // 0..255
    const int bt  = k & 3;                  // 0..3

    const float* __restrict__ FVi = FV + (size_t)i * 256 * 1024;

    floatx16 acc[8];
#pragma unroll
    for (int nt = 0; nt < 8; ++nt)
#pragma unroll
        for (int j = 0; j < 16; ++j) acc[nt][j] = 0.0f;

    const int am = tid >> 1, akg = tid & 1;  // A staging (tid < 128)

    // B staging mapping: thread owns n-subgroup n8 = tid>>8 (8 rows) and
    // cols [c0, c0+4), c0 = (tid&255)*4. 8x float4 per chunk.
    const int n8 = tid >> 8;
    const int c0 = (tid & 255) * 4;

    // ---- prefetch chunk 0 into registers ----
    float4 pv4[8];
    float4 pa0, pa1;
    {
        const float* src = FVi + (size_t)(n8 * 8) * 1024 + c0;
#pragma unroll
        for (int r = 0; r < 8; ++r) pv4[r] = *(const float4*)(src + (size_t)r * 1024);
    }
    if (tid < 128) {
        const float* ap = Mf + (size_t)(bt * 64 + am) * 256 + akg * 8;
        pa0 = *(const float4*)(ap);
        pa1 = *(const float4*)(ap + 4);
    }

#pragma unroll 1
    for (int kt = 0; kt < 16; ++kt) {
        __syncthreads();  // drains prefetch (issued a full compute-phase ago)
        // ---- store staged chunk to LDS (fp32 M split to hi/lo here) ----
        if (tid < 128) {
            half8 hi, lo;
#pragma unroll
            for (int j = 0; j < 4; ++j) {
                _Float16 h, l;
                split_f32((&pa0.x)[j], h, l);
                hi[j] = h; lo[j] = l;
            }
#pragma unroll
            for (int j = 0; j < 4; ++j) {
                _Float16 h, l;
                split_f32((&pa1.x)[j], h, l);
                hi[4 + j] = h; lo[4 + j] = l;
            }
            *(half8*)&AsHi[(akg * 64 + am) * 8] = hi;
            *(half8*)&AsLo[(akg * 64 + am) * 8] = lo;
        }
        // B: in-register 8x4 transpose -> 4 half8 stores (swizzled banks)
#pragma unroll
        for (int j = 0; j < 4; ++j) {
            half8 h;
#pragma unroll
            for (int r = 0; r < 8; ++r) h[r] = (_Float16)((&pv4[r].x)[j]);
            const int byte_off = (n8 * 1024 + c0 + j) * 16;
            *(half8*)((char*)Bs + bs_swz(byte_off)) = h;
        }
        __syncthreads();
        // ---- prefetch next chunk (overlaps with compute below) ----
        if (kt + 1 < 16) {
            const float* src = FVi + (size_t)((kt + 1) * 16 + n8 * 8) * 1024 + c0;
#pragma unroll
            for (int r = 0; r < 8; ++r) pv4[r] = *(const float4*)(src + (size_t)r * 1024);
            if (tid < 128) {
                const float* ap = Mf + (size_t)(bt * 64 + am) * 256 + (kt + 1) * 16 + akg * 8;
                pa0 = *(const float4*)(ap);
                pa1 = *(const float4*)(ap + 4);
            }
        }
        // ---- compute: 8 n-tiles x (hi,lo) MFMA ----
        const half8 ah = *(half8*)&AsHi[(l5 * 64 + wy * 32 + l31) * 8];
        const half8 al = *(half8*)&AsLo[(l5 * 64 + wy * 32 + l31) * 8];
#pragma unroll
        for (int nt = 0; nt < 8; ++nt) {
            const int byte_off = (l5 * 1024 + wx * 256 + nt * 32 + l31) * 16;
            const half8 b = *(const half8*)((const char*)Bs + bs_swz(byte_off));
            acc[nt] = __builtin_amdgcn_mfma_f32_32x32x16_f16(ah, b, acc[nt], 0, 0, 0);
            acc[nt] = __builtin_amdgcn_mfma_f32_32x32x16_f16(al, b, acc[nt], 0, 0, 0);
        }
    }

    // ---- softmax over d (rows span 4 wx waves) ----
    // lane holds: col = wx*256 + nt*32 + l31 ; row = wy*32 + (reg&3)+8*(reg>>2)+4*l5
    float st[16];
#pragma unroll
    for (int reg = 0; reg < 16; ++reg) {
        float v = acc[0][reg];
#pragma unroll
        for (int nt = 1; nt < 8; ++nt) v = fmaxf(v, acc[nt][reg]);
#pragma unroll
        for (int off = 1; off < 32; off <<= 1) v = fmaxf(v, __shfl_xor(v, off));
        st[reg] = v;
    }
    if (l31 == 0) {
#pragma unroll
        for (int reg = 0; reg < 16; ++reg) {
            const int row = wy * 32 + (reg & 3) + 8 * (reg >> 2) + 4 * l5;
            red1[row * 4 + wx] = st[reg];
        }
    }
    __syncthreads();
    float rmax[16];
#pragma unroll
    for (int reg = 0; reg < 16; ++reg) {
        const int row = wy * 32 + (reg & 3) + 8 * (reg >> 2) + 4 * l5;
        const float4 m4 = *(const float4*)&red1[row * 4];
        rmax[reg] = fmaxf(fmaxf(m4.x, m4.y), fmaxf(m4.z, m4.w));
    }
#pragma unroll
    for (int reg = 0; reg < 16; ++reg) {
        float s = 0.0f;
#pragma unroll
        for (int nt = 0; nt < 8; ++nt) {
            const float p = __expf(acc[nt][reg] - rmax[reg]);
            acc[nt][reg] = p;
            s += p;
        }
#pragma unroll
        for (int off = 1; off < 32; off <<= 1) s += __shfl_xor(s, off);
        st[reg] = s;
    }
    if (l31 == 0) {
#pragma unroll
        for (int reg = 0; reg < 16; ++reg) {
            const int row = wy * 32 + (reg & 3) + 8 * (reg >> 2) + 4 * l5;
            red2[row * 4 + wx] = st[reg];
        }
    }
    __syncthreads();
    float inv[16];
#pragma unroll
    for (int reg = 0; reg < 16; ++reg) {
        const int row = wy * 32 + (reg & 3) + 8 * (reg >> 2) + 4 * l5;
        const float4 s4 = *(const float4*)&red2[row * 4];
        inv[reg] = 1.0f / (s4.x + s4.y + s4.z + s4.w);
    }

    // ---- write W (non-temporal), accumulate context ----
    float csum[8];
#pragma unroll
    for (int nt = 0; nt < 8; ++nt) csum[nt] = 0.0f;

    const int rowbase = bt * 64 + wy * 32;
#pragma unroll
    for (int nt = 0; nt < 8; ++nt) {
        const int col = wx * 256 + nt * 32 + l31;
#pragma unroll
        for (int reg = 0; reg < 16; ++reg) {
            const int row = (reg & 3) + 8 * (reg >> 2) + 4 * l5;
            const float wv = acc[nt][reg] * inv[reg];
            __builtin_nontemporal_store(
                wv, &Wout[((size_t)(i * 256 + rowbase + row)) * 1024 + col]);
            const float fv = FVi[(size_t)(rowbase + row) * 1024 + col];
            csum[nt] += wv * fv;
        }
    }
#pragma unroll
    for (int nt = 0; nt < 8; ++nt) {
        const float v = csum[nt] + __shfl_xor(csum[nt], 32);
        if (l5 == 0)
            atomicAdd(&ctx[(size_t)i * 1024 + wx * 256 + nt * 32 + l31], v);
    }
}

// ---------------------------------------------------------------------------
extern "C" void kernel_launch(void* const* d_in, const int* in_sizes, int n_in,
                              void* d_out, int out_size, void* d_ws, size_t ws_size,
                              hipStream_t stream)
{
    const float* FV    = (const float*)d_in[0];  // [256,256,1024]
    const float* state = (const float*)d_in[1];  // [256,1024]
    const float* Q     = (const float*)d_in[2];  // [1024,1024]
    const float* Km    = (const float*)d_in[3];  // [1024,256]

    float* out = (float*)d_out;
    float* ctx = out;                 // [256,1024]
    float* W   = out + 256 * 1024;    // [256,256,1024]

    char* ws = (char*)d_ws;
    float* A1 = (float*)ws;               // [256,1024] fp32, 1 MB
    float* Mf = (float*)(ws + (1 << 20)); // [256,256]  fp32, 256 KB

    // split-K accumulators + ctx atomics -> zero them
    (void)hipMemsetAsync(ws, 0, (1 << 20) + (1 << 18), stream);
    (void)hipMemsetAsync(ctx, 0, 256 * 1024 * sizeof(float), stream);

    // A1 = state @ Q^T   (B stored [N,K]: Q[s,t], contract t), split-K x8
    gemm_splitk<true><<<dim3(16, 4, 8), 256, 0, stream>>>(
        state, Q, A1, 1024, 1024, 128);

    // M = A1 @ K  (B stored [K,N]), split-K x16
    gemm_splitk<false><<<dim3(4, 4, 16), 256, 0, stream>>>(
        A1, Km, Mf, 1024, 256, 64);

    // fused logits -> softmax -> W + ctx (R9 structure, nt W-stores)
    fused_attn<<<dim3(1024), 512, 0, stream>>>(FV, Mf, ctx, W);
}

// Round 12
// 576.303 us; speedup vs baseline: 2.4710x; 1.0118x over previous
//
#include <hip/hip_runtime.h>

// Problem constants: B=N=256, D=S=1024
// out = [ctx 256*1024 fp32 ; W 256*256*1024 fp32]

typedef _Float16 half8 __attribute__((ext_vector_type(8)));
typedef float floatx16 __attribute__((ext_vector_type(16)));

static __device__ __forceinline__ void split_f32(float x, _Float16& hi, _Float16& lo) {
    _Float16 h = (_Float16)x;
    hi = h;
    lo = (_Float16)(x - (float)h);
}

// ---------------------------------------------------------------------------
// Split-K small GEMM (R6, proven): C[M,N] += A[M,K-slice] @ B, fp32 atomicAdd
// epilogue. fp32 in, hi/lo fp16 split on BOTH operands (3 MFMAs).
// Tile 64x64, 256 threads, BK=32.
// ---------------------------------------------------------------------------
template <bool BT>
__global__ __launch_bounds__(256, 2) void gemm_splitk(
    const float* __restrict__ Ag, const float* __restrict__ Bg,
    float* __restrict__ Cf, int Kdim, int Ndim, int KC)
{
    __shared__ __align__(16) _Float16 AsHi[4 * 64 * 8];
    __shared__ __align__(16) _Float16 AsLo[4 * 64 * 8];
    __shared__ __align__(16) _Float16 BsHi[4 * 64 * 8];
    __shared__ __align__(16) _Float16 BsLo[4 * 64 * 8];

    const int tid  = threadIdx.x;
    const int lane = tid & 63;
    const int wave = tid >> 6;
    const int wy = wave >> 1, wx = wave & 1;
    const int l31 = lane & 31, l5 = lane >> 5;
    const int m0 = blockIdx.y * 64, n0 = blockIdx.x * 64;
    const int kt0 = (blockIdx.z * KC) >> 5;

    floatx16 acc;
#pragma unroll
    for (int j = 0; j < 16; ++j) acc[j] = 0.0f;

    const int sA_m  = tid >> 2;
    const int sA_kg = tid & 3;
    const int sB_n  = tid & 63;
    const int sB_kg = tid >> 6;

    const int nkt = KC / 32;
#pragma unroll 1
    for (int kt2 = 0; kt2 < nkt; ++kt2) {
        const int kt = kt0 + kt2;
        __syncthreads();
        {
            const float* src = Ag + (size_t)(m0 + sA_m) * Kdim + kt * 32 + sA_kg * 8;
            half8 hi, lo;
#pragma unroll
            for (int j = 0; j < 8; ++j) {
                _Float16 h, l;
                split_f32(src[j], h, l);
                hi[j] = h; lo[j] = l;
            }
            *(half8*)&AsHi[(sA_kg * 64 + sA_m) * 8] = hi;
            *(half8*)&AsLo[(sA_kg * 64 + sA_m) * 8] = lo;
        }
        if constexpr (BT) {
            const float* src = Bg + (size_t)(n0 + sA_m) * Kdim + kt * 32 + sA_kg * 8;
            half8 hi, lo;
#pragma unroll
            for (int j = 0; j < 8; ++j) {
                _Float16 h, l;
                split_f32(src[j], h, l);
                hi[j] = h; lo[j] = l;
            }
            *(half8*)&BsHi[(sA_kg * 64 + sA_m) * 8] = hi;
            *(half8*)&BsLo[(sA_kg * 64 + sA_m) * 8] = lo;
        } else {
            const float* src = Bg + (size_t)(kt * 32 + sB_kg * 8) * Ndim + n0 + sB_n;
            half8 hi, lo;
#pragma unroll
            for (int j = 0; j < 8; ++j) {
                _Float16 h, l;
                split_f32(src[(size_t)j * Ndim], h, l);
                hi[j] = h; lo[j] = l;
            }
            *(half8*)&BsHi[(sB_kg * 64 + sB_n) * 8] = hi;
            *(half8*)&BsLo[(sB_kg * 64 + sB_n) * 8] = lo;
        }
        __syncthreads();
#pragma unroll
        for (int ks = 0; ks < 2; ++ks) {
            const int kg = ks * 2 + l5;
            const half8 ah = *(half8*)&AsHi[(kg * 64 + wy * 32 + l31) * 8];
            const half8 al = *(half8*)&AsLo[(kg * 64 + wy * 32 + l31) * 8];
            const half8 bh = *(half8*)&BsHi[(kg * 64 + wx * 32 + l31) * 8];
            const half8 bl = *(half8*)&BsLo[(kg * 64 + wx * 32 + l31) * 8];
            acc = __builtin_amdgcn_mfma_f32_32x32x16_f16(ah, bh, acc, 0, 0, 0);
            acc = __builtin_amdgcn_mfma_f32_32x32x16_f16(ah, bl, acc, 0, 0, 0);
            acc = __builtin_amdgcn_mfma_f32_32x32x16_f16(al, bh, acc, 0, 0, 0);
        }
    }

    // C/D layout (verified): col = lane&31, row = (reg&3) + 8*(reg>>2) + 4*(lane>>5)
#pragma unroll
    for (int reg = 0; reg < 16; ++reg) {
        const int row = m0 + wy * 32 + (reg & 3) + 8 * (reg >> 2) + 4 * l5;
        const int col = n0 + wx * 32 + l31;
        atomicAdd(&Cf[(size_t)row * Ndim + col], acc[reg]);
    }
}

// Bank swizzle for Bs (proven R9): XOR bits[6:4] with bits[9:7]. Involution;
// applied identically on store and read, so placement is self-consistent.
static __device__ __forceinline__ int bs_swz(int byte_off) {
    return byte_off ^ (((byte_off >> 7) & 7) << 4);
}

// ---------------------------------------------------------------------------
// Fused R12 = R9 (best, 255 us) + SIBLING CHUNK STAGGER.
// R0-R11 established: traffic is at the algorithmic minimum, occupancy is
// falsified 3x, issue shape fixed, nt-stores negative. Remaining suspect:
// the lockstep convoy -- all 4 siblings of an i demand the SAME chunk lines
// at the SAME time, so every chunk is an HBM-latency multicast + TCC
// same-line replay for all four; nobody ever finds warm L2.
// Fix: K-accumulation commutes, so sibling bt processes chunks in rotated
// order c = (kt + bt) & 15. Siblings occupy 4 CONSECUTIVE chunks; the unique
// leader per chunk eats HBM latency, the other 3 hit L2 warm 1-3 steps later
// (~250 cy, covered by compute). Window: ~512 KB fresh/step x 3-step
// retention ~ 2 MB < 4 MB L2 -> traffic guard holds (offset=1, not 4).
// Everything else bit-identical to R9 (plain W stores).
// ---------------------------------------------------------------------------
__global__ __launch_bounds__(512, 2) void fused_attn(
    const float* __restrict__ FV, const float* __restrict__ Mf,
    float* __restrict__ ctx, float* __restrict__ Wout)
{
    __shared__ __align__(16) _Float16 AsHi[2 * 64 * 8];
    __shared__ __align__(16) _Float16 AsLo[2 * 64 * 8];
    __shared__ __align__(16) _Float16 Bs[2 * 1024 * 8];
    __shared__ __align__(16) float red1[64 * 4];
    __shared__ __align__(16) float red2[64 * 4];

    const int tid  = threadIdx.x;
    const int lane = tid & 63;
    const int wave = tid >> 6;
    const int wx = wave & 3;   // d-slice (256 cols)
    const int wy = wave >> 2;  // m-half (32 rows)
    const int l31 = lane & 31, l5 = lane >> 5;

    // XCD-aware swizzle: all 4 bt of an i share one XCD.
    const int w   = blockIdx.x;   // 0..1023
    const int xcd = w & 7;
    const int k   = w >> 3;       // 0..127
    const int i   = (xcd << 5) + (k >> 2);  // 0..255
    const int bt  = k & 3;                  // 0..3

    const float* __restrict__ FVi = FV + (size_t)i * 256 * 1024;

    floatx16 acc[8];
#pragma unroll
    for (int nt = 0; nt < 8; ++nt)
#pragma unroll
        for (int j = 0; j < 16; ++j) acc[nt][j] = 0.0f;

    const int am = tid >> 1, akg = tid & 1;  // A staging (tid < 128)

    // B staging mapping: thread owns n-subgroup n8 = tid>>8 (8 rows) and
    // cols [c0, c0+4), c0 = (tid&255)*4. 8x float4 per chunk.
    const int n8 = tid >> 8;
    const int c0 = (tid & 255) * 4;

    // ---- prefetch staggered chunk 0 into registers ----
    float4 pv4[8];
    float4 pa0, pa1;
    {
        const int c = bt & 15;  // stagger: sibling bt starts at chunk bt
        const float* src = FVi + (size_t)(c * 16 + n8 * 8) * 1024 + c0;
#pragma unroll
        for (int r = 0; r < 8; ++r) pv4[r] = *(const float4*)(src + (size_t)r * 1024);
        if (tid < 128) {
            const float* ap = Mf + (size_t)(bt * 64 + am) * 256 + c * 16 + akg * 8;
            pa0 = *(const float4*)(ap);
            pa1 = *(const float4*)(ap + 4);
        }
    }

#pragma unroll 1
    for (int kt = 0; kt < 16; ++kt) {
        __syncthreads();  // drains prefetch (issued a full compute-phase ago)
        // ---- store staged chunk to LDS (fp32 M split to hi/lo here) ----
        if (tid < 128) {
            half8 hi, lo;
#pragma unroll
            for (int j = 0; j < 4; ++j) {
                _Float16 h, l;
                split_f32((&pa0.x)[j], h, l);
                hi[j] = h; lo[j] = l;
            }
#pragma unroll
            for (int j = 0; j < 4; ++j) {
                _Float16 h, l;
                split_f32((&pa1.x)[j], h, l);
                hi[4 + j] = h; lo[4 + j] = l;
            }
            *(half8*)&AsHi[(akg * 64 + am) * 8] = hi;
            *(half8*)&AsLo[(akg * 64 + am) * 8] = lo;
        }
        // B: in-register 8x4 transpose -> 4 half8 stores (swizzled banks)
#pragma unroll
        for (int j = 0; j < 4; ++j) {
            half8 h;
#pragma unroll
            for (int r = 0; r < 8; ++r) h[r] = (_Float16)((&pv4[r].x)[j]);
            const int byte_off = (n8 * 1024 + c0 + j) * 16;
            *(half8*)((char*)Bs + bs_swz(byte_off)) = h;
        }
        __syncthreads();
        // ---- prefetch next staggered chunk (overlaps with compute below) ----
        if (kt + 1 < 16) {
            const int c = (kt + 1 + bt) & 15;  // stagger
            const float* src = FVi + (size_t)(c * 16 + n8 * 8) * 1024 + c0;
#pragma unroll
            for (int r = 0; r < 8; ++r) pv4[r] = *(const float4*)(src + (size_t)r * 1024);
            if (tid < 128) {
                const float* ap = Mf + (size_t)(bt * 64 + am) * 256 + c * 16 + akg * 8;
                pa0 = *(const float4*)(ap);
                pa1 = *(const float4*)(ap + 4);
            }
        }
        // ---- compute: 8 n-tiles x (hi,lo) MFMA (chunk order irrelevant) ----
        const half8 ah = *(half8*)&AsHi[(l5 * 64 + wy * 32 + l31) * 8];
        const half8 al = *(half8*)&AsLo[(l5 * 64 + wy * 32 + l31) * 8];
#pragma unroll
        for (int nt = 0; nt < 8; ++nt) {
            const int byte_off = (l5 * 1024 + wx * 256 + nt * 32 + l31) * 16;
            const half8 b = *(const half8*)((const char*)Bs + bs_swz(byte_off));
            acc[nt] = __builtin_amdgcn_mfma_f32_32x32x16_f16(ah, b, acc[nt], 0, 0, 0);
            acc[nt] = __builtin_amdgcn_mfma_f32_32x32x16_f16(al, b, acc[nt], 0, 0, 0);
        }
    }

    // ---- softmax over d (rows span 4 wx waves) ----
    // lane holds: col = wx*256 + nt*32 + l31 ; row = wy*32 + (reg&3)+8*(reg>>2)+4*l5
    float st[16];
#pragma unroll
    for (int reg = 0; reg < 16; ++reg) {
        float v = acc[0][reg];
#pragma unroll
        for (int nt = 1; nt < 8; ++nt) v = fmaxf(v, acc[nt][reg]);
#pragma unroll
        for (int off = 1; off < 32; off <<= 1) v = fmaxf(v, __shfl_xor(v, off));
        st[reg] = v;
    }
    if (l31 == 0) {
#pragma unroll
        for (int reg = 0; reg < 16; ++reg) {
            const int row = wy * 32 + (reg & 3) + 8 * (reg >> 2) + 4 * l5;
            red1[row * 4 + wx] = st[reg];
        }
    }
    __syncthreads();
    float rmax[16];
#pragma unroll
    for (int reg = 0; reg < 16; ++reg) {
        const int row = wy * 32 + (reg & 3) + 8 * (reg >> 2) + 4 * l5;
        const float4 m4 = *(const float4*)&red1[row * 4];
        rmax[reg] = fmaxf(fmaxf(m4.x, m4.y), fmaxf(m4.z, m4.w));
    }
#pragma unroll
    for (int reg = 0; reg < 16; ++reg) {
        float s = 0.0f;
#pragma unroll
        for (int nt = 0; nt < 8; ++nt) {
            const float p = __expf(acc[nt][reg] - rmax[reg]);
            acc[nt][reg] = p;
            s += p;
        }
#pragma unroll
        for (int off = 1; off < 32; off <<= 1) s += __shfl_xor(s, off);
        st[reg] = s;
    }
    if (l31 == 0) {
#pragma unroll
        for (int reg = 0; reg < 16; ++reg) {
            const int row = wy * 32 + (reg & 3) + 8 * (reg >> 2) + 4 * l5;
            red2[row * 4 + wx] = st[reg];
        }
    }
    __syncthreads();
    float inv[16];
#pragma unroll
    for (int reg = 0; reg < 16; ++reg) {
        const int row = wy * 32 + (reg & 3) + 8 * (reg >> 2) + 4 * l5;
        const float4 s4 = *(const float4*)&red2[row * 4];
        inv[reg] = 1.0f / (s4.x + s4.y + s4.z + s4.w);
    }

    // ---- write W, accumulate context ----
    float csum[8];
#pragma unroll
    for (int nt = 0; nt < 8; ++nt) csum[nt] = 0.0f;

    const int rowbase = bt * 64 + wy * 32;
#pragma unroll
    for (int nt = 0; nt < 8; ++nt) {
        const int col = wx * 256 + nt * 32 + l31;
#pragma unroll
        for (int reg = 0; reg < 16; ++reg) {
            const int row = (reg & 3) + 8 * (reg >> 2) + 4 * l5;
            const float wv = acc[nt][reg] * inv[reg];
            Wout[((size_t)(i * 256 + rowbase + row)) * 1024 + col] = wv;
            const float fv = FVi[(size_t)(rowbase + row) * 1024 + col];
            csum[nt] += wv * fv;
        }
    }
#pragma unroll
    for (int nt = 0; nt < 8; ++nt) {
        const float v = csum[nt] + __shfl_xor(csum[nt], 32);
        if (l5 == 0)
            atomicAdd(&ctx[(size_t)i * 1024 + wx * 256 + nt * 32 + l31], v);
    }
}

// ---------------------------------------------------------------------------
extern "C" void kernel_launch(void* const* d_in, const int* in_sizes, int n_in,
                              void* d_out, int out_size, void* d_ws, size_t ws_size,
                              hipStream_t stream)
{
    const float* FV    = (const float*)d_in[0];  // [256,256,1024]
    const float* state = (const float*)d_in[1];  // [256,1024]
    const float* Q     = (const float*)d_in[2];  // [1024,1024]
    const float* Km    = (const float*)d_in[3];  // [1024,256]

    float* out = (float*)d_out;
    float* ctx = out;                 // [256,1024]
    float* W   = out + 256 * 1024;    // [256,256,1024]

    char* ws = (char*)d_ws;
    float* A1 = (float*)ws;               // [256,1024] fp32, 1 MB
    float* Mf = (float*)(ws + (1 << 20)); // [256,256]  fp32, 256 KB

    // split-K accumulators + ctx atomics -> zero them
    (void)hipMemsetAsync(ws, 0, (1 << 20) + (1 << 18), stream);
    (void)hipMemsetAsync(ctx, 0, 256 * 1024 * sizeof(float), stream);

    // A1 = state @ Q^T   (B stored [N,K]: Q[s,t], contract t), split-K x8
    gemm_splitk<true><<<dim3(16, 4, 8), 256, 0, stream>>>(
        state, Q, A1, 1024, 1024, 128);

    // M = A1 @ K  (B stored [K,N]), split-K x16
    gemm_splitk<false><<<dim3(4, 4, 16), 256, 0, stream>>>(
        A1, Km, Mf, 1024, 256, 64);

    // fused logits -> softmax -> W + ctx (R9 structure + sibling stagger)
    fused_attn<<<dim3(1024), 512, 0, stream>>>(FV, Mf, ctx, W);
}